// Round 2
// baseline (3738.013 us; speedup 1.0000x reference)
//
#include <hip/hip_runtime.h>
#include <hip/hip_bf16.h>

#define H 128
#define D_IN 256
#define NGRAPH 8

// ---- order-preserving float<->unsigned encoding for atomicMax-based segment_max
__device__ __forceinline__ unsigned fenc(float f) {
  unsigned u = __float_as_uint(f);
  return (u & 0x80000000u) ? ~u : (u | 0x80000000u);
}
__device__ __forceinline__ float fdec(unsigned e) {
  unsigned v = (e & 0x80000000u) ? (e & 0x7FFFFFFFu) : ~e;
  return __uint_as_float(v);
}

__global__ void init_kernel(int* __restrict__ offsets, unsigned* __restrict__ wsi, int n1) {
  int i = blockIdx.x * blockDim.x + threadIdx.x;
  if (i < n1) offsets[i] = 0;
  if (i < 3 * NGRAPH) wsi[i] = 0u;  // 0 < fenc(any finite float)
}

__global__ void count_kernel(const int* __restrict__ dst, int* __restrict__ offsets, int E) {
  int i = blockIdx.x * blockDim.x + threadIdx.x;
  int stride = gridDim.x * blockDim.x;
  for (int e = i; e < E; e += stride) atomicAdd(&offsets[dst[e]], 1);
}

// single-block exclusive scan of offsets[0..n) in place; cursor gets a copy; offsets[n]=total
__global__ void scan_kernel(int* __restrict__ offsets, int* __restrict__ cursor, int n) {
  __shared__ int sdata[1024];
  __shared__ int s_running;
  int tid = threadIdx.x;
  if (tid == 0) s_running = 0;
  __syncthreads();
  for (int base = 0; base < n; base += 1024) {
    int i = base + tid;
    int v = (i < n) ? offsets[i] : 0;
    sdata[tid] = v;
    __syncthreads();
    for (int off = 1; off < 1024; off <<= 1) {
      int t = (tid >= off) ? sdata[tid - off] : 0;
      __syncthreads();
      sdata[tid] += t;
      __syncthreads();
    }
    int excl = sdata[tid] - v + s_running;
    if (i < n) { offsets[i] = excl; cursor[i] = excl; }
    __syncthreads();
    if (tid == 1023) s_running = excl + v;  // old running + chunk inclusive total
    __syncthreads();
  }
  if (tid == 0) offsets[n] = s_running;
}

__global__ void fill_kernel(const int* __restrict__ src, const int* __restrict__ dst,
                            int* __restrict__ cursor, int* __restrict__ esrc, int E) {
  int i = blockIdx.x * blockDim.x + threadIdx.x;
  int stride = gridDim.x * blockDim.x;
  for (int e = i; e < E; e += stride) {
    int d = dst[e];
    int p = atomicAdd(&cursor[d], 1);
    esrc[p] = src[e];
  }
}

// h = relu(bn(x @ w_first + b)); node_pred = h.w_lin0 + b_lin0; wsi[0] max
__global__ void __launch_bounds__(128)
first_layer_kernel(const float* __restrict__ x, const float* __restrict__ w,
                   const float* __restrict__ bias, const float* __restrict__ bn,
                   const float* __restrict__ wlin, const float* __restrict__ blin,
                   const int* __restrict__ batch,
                   __hip_bfloat16* __restrict__ h, float* __restrict__ node_pred,
                   unsigned* __restrict__ wsi) {
  int i = blockIdx.x;
  int f = threadIdx.x;  // 0..127
  __shared__ float xs[D_IN];
  __shared__ float red[2];
  float2 v = ((const float2*)(x + (size_t)i * D_IN))[f];
  xs[2 * f] = v.x; xs[2 * f + 1] = v.y;
  __syncthreads();
  float acc = bias[f];
#pragma unroll 8
  for (int k = 0; k < D_IN; ++k) acc = fmaf(xs[k], w[k * H + f], acc);
  float gamma = bn[f], beta = bn[H + f], mean = bn[2 * H + f], var = bn[3 * H + f];
  float hv = (acc - mean) * rsqrtf(var + 1e-5f) * gamma + beta;
  hv = fmaxf(hv, 0.0f);
  h[(size_t)i * H + f] = __float2bfloat16(hv);
  float c = hv * wlin[f];
#pragma unroll
  for (int off = 32; off > 0; off >>= 1) c += __shfl_down(c, off);
  if ((f & 63) == 0) red[f >> 6] = c;
  __syncthreads();
  if (f == 0) {
    float np = red[0] + red[1] + blin[0];
    node_pred[i] = np;
    atomicMax(&wsi[batch[i]], fenc(np));
  }
}

// tmp[i] = h[i] + sum_{j in-edges} h[src_j]   (bf16 storage, f32 accumulate)
__global__ void __launch_bounds__(256)
agg_kernel(const __hip_bfloat16* __restrict__ h, const int* __restrict__ offsets,
           const int* __restrict__ esrc, __hip_bfloat16* __restrict__ tmp, int n) {
  int node = blockIdx.x * 4 + (threadIdx.x >> 6);
  if (node >= n) return;
  int lane = threadIdx.x & 63;  // 2 features per lane
  const unsigned* hw = (const unsigned*)h;
  size_t base = (size_t)node * (H / 2) + lane;
  unsigned u = hw[base];
  float a0 = __uint_as_float((u & 0xFFFFu) << 16);
  float a1 = __uint_as_float(u & 0xFFFF0000u);
  int s = offsets[node], e = offsets[node + 1];
  for (int j = s; j < e; ++j) {
    int sj = esrc[j];
    unsigned v2 = hw[(size_t)sj * (H / 2) + lane];
    a0 += __uint_as_float((v2 & 0xFFFFu) << 16);
    a1 += __uint_as_float(v2 & 0xFFFF0000u);
  }
  __hip_bfloat16 r0 = __float2bfloat16(a0), r1 = __float2bfloat16(a1);
  unsigned short u0 = *reinterpret_cast<unsigned short*>(&r0);
  unsigned short u1 = *reinterpret_cast<unsigned short*>(&r1);
  ((unsigned*)tmp)[base] = ((unsigned)u1 << 16) | (unsigned)u0;
}

// h = relu(bn(tmp @ W + b)); np_sub head; node_pred += ; wsi[l+1] max
__global__ void __launch_bounds__(128)
conv_kernel(const __hip_bfloat16* __restrict__ tmp, const float* __restrict__ w,
            const float* __restrict__ bias, const float* __restrict__ bn,
            const float* __restrict__ wlin, const float* __restrict__ blin, int lidx,
            const int* __restrict__ batch,
            __hip_bfloat16* __restrict__ h, float* __restrict__ node_pred,
            unsigned* __restrict__ wsi) {
  int i = blockIdx.x;
  int f = threadIdx.x;  // 0..127
  __shared__ float row[H];
  __shared__ float red[2];
  row[f] = __bfloat162float(tmp[(size_t)i * H + f]);
  __syncthreads();
  float acc = bias[f];
#pragma unroll 8
  for (int k = 0; k < H; ++k) acc = fmaf(row[k], w[k * H + f], acc);
  float gamma = bn[f], beta = bn[H + f], mean = bn[2 * H + f], var = bn[3 * H + f];
  float hv = fmaxf((acc - mean) * rsqrtf(var + 1e-5f) * gamma + beta, 0.0f);
  h[(size_t)i * H + f] = __float2bfloat16(hv);
  float c = hv * wlin[f];
#pragma unroll
  for (int off = 32; off > 0; off >>= 1) c += __shfl_down(c, off);
  if ((f & 63) == 0) red[f >> 6] = c;
  __syncthreads();
  if (f == 0) {
    float np = red[0] + red[1] + blin[lidx];
    node_pred[i] += np;
    atomicMax(&wsi[batch[i]], fenc(np));
  }
}

__global__ void finalize_kernel(const unsigned* __restrict__ wsi, float* __restrict__ out) {
  int g = threadIdx.x;
  if (g < NGRAPH) out[g] = fdec(wsi[g]) + fdec(wsi[NGRAPH + g]) + fdec(wsi[2 * NGRAPH + g]);
}

extern "C" void kernel_launch(void* const* d_in, const int* in_sizes, int n_in,
                              void* d_out, int out_size, void* d_ws, size_t ws_size,
                              hipStream_t stream) {
  const float* x        = (const float*)d_in[0];
  const int*   ei       = (const int*)d_in[1];
  const int*   batch    = (const int*)d_in[2];
  const float* w_first  = (const float*)d_in[3];
  const float* b_first  = (const float*)d_in[4];
  const float* bn_first = (const float*)d_in[5];
  const float* w_conv   = (const float*)d_in[6];
  const float* b_conv   = (const float*)d_in[7];
  const float* bn_conv  = (const float*)d_in[8];
  const float* w_lin    = (const float*)d_in[9];
  const float* b_lin    = (const float*)d_in[10];
  float* out = (float*)d_out;

  const int N = in_sizes[0] / D_IN;
  const int E = in_sizes[1] / 2;
  const int* src = ei;
  const int* dst = ei + E;

  char* ws = (char*)d_ws;
  __hip_bfloat16* h   = (__hip_bfloat16*)ws;
  __hip_bfloat16* tmp = h + (size_t)N * H;
  int* offsets = (int*)(tmp + (size_t)N * H);
  int* cursor  = offsets + (N + 1);
  int* esrc    = cursor + N;
  unsigned* wsi = (unsigned*)(esrc + E);
  float* node_pred = out + NGRAPH;

  init_kernel<<<(N + 256) / 256, 256, 0, stream>>>(offsets, wsi, N + 1);
  count_kernel<<<1024, 256, 0, stream>>>(dst, offsets, E);
  scan_kernel<<<1, 1024, 0, stream>>>(offsets, cursor, N);
  fill_kernel<<<1024, 256, 0, stream>>>(src, dst, cursor, esrc, E);
  first_layer_kernel<<<N, H, 0, stream>>>(x, w_first, b_first, bn_first, w_lin, b_lin,
                                          batch, h, node_pred, wsi);
  for (int l = 0; l < 2; ++l) {
    agg_kernel<<<(N + 3) / 4, 256, 0, stream>>>(h, offsets, esrc, tmp, N);
    conv_kernel<<<N, H, 0, stream>>>(tmp, w_conv + (size_t)l * H * H, b_conv + (size_t)l * H,
                                     bn_conv + (size_t)l * 4 * H, w_lin + (size_t)(l + 1) * H,
                                     b_lin, l + 1, batch, h, node_pred,
                                     wsi + (size_t)(l + 1) * NGRAPH);
  }
  finalize_kernel<<<1, 64, 0, stream>>>(wsi, out);
}

// Round 3
// 508.587 us; speedup vs baseline: 7.3498x; 7.3498x over previous
//
#include <hip/hip_runtime.h>
#include <hip/hip_bf16.h>

#define H 128
#define D_IN 256
#define NGRAPH 8

typedef __attribute__((ext_vector_type(8))) short bf16x8;
typedef __attribute__((ext_vector_type(4))) float f32x4;
typedef __attribute__((ext_vector_type(4))) int i32x4;

// ---- order-preserving float<->unsigned encoding for atomicMax-based segment_max
__device__ __forceinline__ unsigned fenc(float f) {
  unsigned u = __float_as_uint(f);
  return (u & 0x80000000u) ? ~u : (u | 0x80000000u);
}
__device__ __forceinline__ float fdec(unsigned e) {
  unsigned v = (e & 0x80000000u) ? (e & 0x7FFFFFFFu) : ~e;
  return __uint_as_float(v);
}
__device__ __forceinline__ unsigned short f2bf(float f) {  // RNE f32->bf16
  unsigned u = __float_as_uint(f);
  unsigned r = u + 0x7FFFu + ((u >> 16) & 1u);
  return (unsigned short)(r >> 16);
}

__global__ void init_kernel(int* __restrict__ offsets, unsigned* __restrict__ wsi, int n1) {
  int i = blockIdx.x * blockDim.x + threadIdx.x;
  if (i < n1) offsets[i] = 0;
  if (i < 3 * NGRAPH) wsi[i] = 0u;  // 0 < fenc(any finite float)
}

__global__ void count_kernel(const int* __restrict__ dst, int* __restrict__ offsets, int E) {
  int i = blockIdx.x * blockDim.x + threadIdx.x;
  int stride = gridDim.x * blockDim.x;
  for (int e = i; e < E; e += stride) atomicAdd(&offsets[dst[e]], 1);
}

// single-block exclusive scan of offsets[0..n) in place; cursor gets a copy; offsets[n]=total
__global__ void scan_kernel(int* __restrict__ offsets, int* __restrict__ cursor, int n) {
  __shared__ int sdata[1024];
  __shared__ int s_running;
  int tid = threadIdx.x;
  if (tid == 0) s_running = 0;
  __syncthreads();
  for (int base = 0; base < n; base += 1024) {
    int i = base + tid;
    int v = (i < n) ? offsets[i] : 0;
    sdata[tid] = v;
    __syncthreads();
    for (int off = 1; off < 1024; off <<= 1) {
      int t = (tid >= off) ? sdata[tid - off] : 0;
      __syncthreads();
      sdata[tid] += t;
      __syncthreads();
    }
    int excl = sdata[tid] - v + s_running;
    if (i < n) { offsets[i] = excl; cursor[i] = excl; }
    __syncthreads();
    if (tid == 1023) s_running = excl + v;
    __syncthreads();
  }
  if (tid == 0) offsets[n] = s_running;
}

__global__ void fill_kernel(const int* __restrict__ src, const int* __restrict__ dst,
                            int* __restrict__ cursor, int* __restrict__ esrc, int E) {
  int i = blockIdx.x * blockDim.x + threadIdx.x;
  int stride = gridDim.x * blockDim.x;
  for (int e = i; e < E; e += stride) {
    int d = dst[e];
    int p = atomicAdd(&cursor[d], 1);
    esrc[p] = src[e];
  }
}

// transpose + convert weights to bf16: wT[n][k] = bf16(w[k][n])
__global__ void prep_weights(const float* __restrict__ wf, const float* __restrict__ wcv,
                             unsigned short* __restrict__ wTf, unsigned short* __restrict__ wTc) {
  int i = blockIdx.x * 256 + threadIdx.x;
  if (i < H * D_IN) {
    int n = i >> 8, k = i & 255;
    wTf[i] = f2bf(wf[k * H + n]);
  } else if (i < H * D_IN + 2 * H * H) {
    int j = i - H * D_IN;
    int l = j >> 14, r = j & 16383;
    int n = r >> 7, k = r & 127;
    wTc[j] = f2bf(wcv[l * H * H + k * H + n]);
  }
}

// Fused GEMM [N x K] @ [K x 128] + bias + BN(eval) + ReLU -> h (bf16),
// plus linear head -> node_pred and per-graph segment-max -> wsi.
// 256 threads = 4 waves in 2x2; wave tile 64x64 via mfma 16x16x32 bf16.
template <int K, bool AF32, bool FIRST>
__global__ void __launch_bounds__(256)
gemm_kernel(const void* __restrict__ Ain, const unsigned short* __restrict__ wT,
            const float* __restrict__ bias, const float* __restrict__ bn,
            const float* __restrict__ wlin, const float* __restrict__ blin, int lidx,
            const int* __restrict__ batch, unsigned short* __restrict__ hout,
            float* __restrict__ node_pred, unsigned* __restrict__ wsi, int N) {
  __shared__ char s_a[4][4096];        // per-wave private: A tile [64 rows][64 B], swizzled
  __shared__ unsigned s_wsi[NGRAPH];
  const int tid = threadIdx.x;
  const int wid = tid >> 6, lane = tid & 63;
  const int wr = wid >> 1, wc = wid & 1;
  const int g = lane >> 4, l15 = lane & 15;
  if (tid < NGRAPH) s_wsi[tid] = 0u;
  __syncthreads();

  char* aw = s_a[wid];
  const int growA = blockIdx.x * 128 + wr * 64 + lane;  // this lane's staging row
  f32x4 acc[4][4] = {};

  for (int k0 = 0; k0 < K; k0 += 32) {
    // ---- stage A chunk [64 rows][32 cols] into LDS (bf16, slot-swizzled)
    if (AF32) {
      const float* xr = (const float*)Ain + (size_t)growA * K + k0;
#pragma unroll
      for (int s = 0; s < 4; ++s) {
        float4 u0 = {0, 0, 0, 0}, u1 = {0, 0, 0, 0};
        if (growA < N) {
          u0 = *(const float4*)(xr + s * 8);
          u1 = *(const float4*)(xr + s * 8 + 4);
        }
        union { unsigned short hh[8]; i32x4 q; } pk;
        pk.hh[0] = f2bf(u0.x); pk.hh[1] = f2bf(u0.y); pk.hh[2] = f2bf(u0.z); pk.hh[3] = f2bf(u0.w);
        pk.hh[4] = f2bf(u1.x); pk.hh[5] = f2bf(u1.y); pk.hh[6] = f2bf(u1.z); pk.hh[7] = f2bf(u1.w);
        *(i32x4*)(aw + lane * 64 + ((s ^ (lane & 3)) << 4)) = pk.q;
      }
    } else {
      const unsigned short* tr = (const unsigned short*)Ain + (size_t)growA * K + k0;
#pragma unroll
      for (int s = 0; s < 4; ++s) {
        i32x4 q = {0, 0, 0, 0};
        if (growA < N) q = *(const i32x4*)(tr + s * 8);
        *(i32x4*)(aw + lane * 64 + ((s ^ (lane & 3)) << 4)) = q;
      }
    }
    // ---- fragments + MFMA (DS ops are in-order within a wave; LDS is wave-private)
    bf16x8 af[4], bfr[4];
#pragma unroll
    for (int m = 0; m < 4; ++m) {
      int r = m * 16 + l15;
      af[m] = *(bf16x8*)(aw + r * 64 + ((g ^ (r & 3)) << 4));
    }
#pragma unroll
    for (int n = 0; n < 4; ++n) {
      int c = wc * 64 + n * 16 + l15;
      bfr[n] = *(const bf16x8*)(wT + (size_t)c * K + k0 + g * 8);
    }
#pragma unroll
    for (int m = 0; m < 4; ++m)
#pragma unroll
      for (int n = 0; n < 4; ++n)
        acc[m][n] = __builtin_amdgcn_mfma_f32_16x16x32_bf16(af[m], bfr[n], acc[m][n], 0, 0, 0);
  }

  // ---- epilogue: bias+BN+ReLU folded to hv = acc*sc + sh
  float sc[4], sh[4];
#pragma unroll
  for (int n = 0; n < 4; ++n) {
    int c = wc * 64 + n * 16 + l15;
    float gam = bn[c], bet = bn[H + c], mu = bn[2 * H + c], va = bn[3 * H + c];
    float rs = rsqrtf(va + 1e-5f);
    sc[n] = gam * rs;
    sh[n] = (bias[c] - mu) * gam * rs + bet;
  }

#pragma unroll
  for (int m = 0; m < 4; ++m) {
    // write this wave's 16x64 output tile (bf16) into its LDS region
#pragma unroll
    for (int n = 0; n < 4; ++n)
#pragma unroll
      for (int j = 0; j < 4; ++j) {
        float hv = fmaxf(acc[m][n][j] * sc[n] + sh[n], 0.f);
        int rr = g * 4 + j;
        *(unsigned short*)(aw + rr * 128 + (n * 16 + l15) * 2) = f2bf(hv);
      }
    // coalesced bf16 h store (16 rows x 64 cols per wave)
    int grb = blockIdx.x * 128 + wr * 64 + m * 16;
#pragma unroll
    for (int it = 0; it < 2; ++it) {
      int bo = lane * 16 + it * 1024;
      int r16 = bo >> 7, inrow = bo & 127;
      if (grb + r16 < N)
        *(i32x4*)((char*)hout + (size_t)(grb + r16) * 256 + wc * 128 + inrow) =
            *(i32x4*)(aw + bo);
    }
    __syncthreads();
    // head: 32 rows (both wr halves) x 128 cols; 8 threads per row
    {
      int rid = tid >> 3, oct = tid & 7;
      int wr2 = rid >> 4, r16 = rid & 15;
      const char* reg = s_a[wr2 * 2 + (oct >> 2)];
      int lb = r16 * 128 + (oct & 3) * 32;
      float sum = 0.f;
#pragma unroll
      for (int half = 0; half < 2; ++half) {
        union { i32x4 q; unsigned short hh[8]; } t;
        t.q = *(const i32x4*)(reg + lb + half * 16);
#pragma unroll
        for (int i = 0; i < 8; ++i) {
          float hv = __uint_as_float(((unsigned)t.hh[i]) << 16);
          sum += hv * wlin[oct * 16 + half * 8 + i];
        }
      }
      sum += __shfl_xor(sum, 1);
      sum += __shfl_xor(sum, 2);
      sum += __shfl_xor(sum, 4);
      int grh = blockIdx.x * 128 + wr2 * 64 + m * 16 + r16;
      if (oct == 0 && grh < N) {
        float np = sum + blin[lidx];
        if (FIRST) node_pred[grh] = np; else node_pred[grh] += np;
        atomicMax(&s_wsi[batch[grh]], fenc(np));
      }
    }
    __syncthreads();
  }
  if (tid < NGRAPH && s_wsi[tid] != 0u) atomicMax(&wsi[tid], s_wsi[tid]);
}

// tmp[i] = h[i] + sum_{j in-edges} h[src_j]   (bf16 storage, f32 accumulate)
__global__ void __launch_bounds__(256)
agg_kernel(const unsigned short* __restrict__ h, const int* __restrict__ offsets,
           const int* __restrict__ esrc, unsigned short* __restrict__ tmp, int n) {
  int node = blockIdx.x * 4 + (threadIdx.x >> 6);
  if (node >= n) return;
  int lane = threadIdx.x & 63;  // 2 features per lane
  const unsigned* hw = (const unsigned*)h;
  size_t base = (size_t)node * (H / 2) + lane;
  unsigned u = hw[base];
  float a0 = __uint_as_float((u & 0xFFFFu) << 16);
  float a1 = __uint_as_float(u & 0xFFFF0000u);
  int s = offsets[node], e = offsets[node + 1];
  for (int j = s; j < e; ++j) {
    int sj = esrc[j];
    unsigned v2 = hw[(size_t)sj * (H / 2) + lane];
    a0 += __uint_as_float((v2 & 0xFFFFu) << 16);
    a1 += __uint_as_float(v2 & 0xFFFF0000u);
  }
  unsigned r = ((unsigned)f2bf(a1) << 16) | (unsigned)f2bf(a0);
  ((unsigned*)tmp)[base] = r;
}

__global__ void finalize_kernel(const unsigned* __restrict__ wsi, float* __restrict__ out) {
  int g = threadIdx.x;
  if (g < NGRAPH) out[g] = fdec(wsi[g]) + fdec(wsi[NGRAPH + g]) + fdec(wsi[2 * NGRAPH + g]);
}

extern "C" void kernel_launch(void* const* d_in, const int* in_sizes, int n_in,
                              void* d_out, int out_size, void* d_ws, size_t ws_size,
                              hipStream_t stream) {
  const float* x        = (const float*)d_in[0];
  const int*   ei       = (const int*)d_in[1];
  const int*   batch    = (const int*)d_in[2];
  const float* w_first  = (const float*)d_in[3];
  const float* b_first  = (const float*)d_in[4];
  const float* bn_first = (const float*)d_in[5];
  const float* w_conv   = (const float*)d_in[6];
  const float* b_conv   = (const float*)d_in[7];
  const float* bn_conv  = (const float*)d_in[8];
  const float* w_lin    = (const float*)d_in[9];
  const float* b_lin    = (const float*)d_in[10];
  float* out = (float*)d_out;

  const int N = in_sizes[0] / D_IN;
  const int E = in_sizes[1] / 2;
  const int* src = ei;
  const int* dst = ei + E;

  char* ws = (char*)d_ws;
  unsigned short* h   = (unsigned short*)ws;            // N*H bf16
  unsigned short* tmp = h + (size_t)N * H;              // N*H bf16
  unsigned short* wTf = tmp + (size_t)N * H;            // 128*256 bf16 (w_first^T)
  unsigned short* wTc = wTf + H * D_IN;                 // 2*128*128 bf16 (w_conv^T)
  int* offsets = (int*)(wTc + 2 * H * H);
  int* cursor  = offsets + (N + 1);
  int* esrc    = cursor + N;
  unsigned* wsi = (unsigned*)(esrc + E);
  float* node_pred = out + NGRAPH;

  const int gemm_grid = (N + 127) / 128;

  init_kernel<<<(N + 256) / 256, 256, 0, stream>>>(offsets, wsi, N + 1);
  count_kernel<<<1024, 256, 0, stream>>>(dst, offsets, E);
  scan_kernel<<<1, 1024, 0, stream>>>(offsets, cursor, N);
  fill_kernel<<<1024, 256, 0, stream>>>(src, dst, cursor, esrc, E);
  prep_weights<<<256, 256, 0, stream>>>(w_first, w_conv, wTf, wTc);

  gemm_kernel<D_IN, true, true><<<gemm_grid, 256, 0, stream>>>(
      x, wTf, b_first, bn_first, w_lin, b_lin, 0, batch, h, node_pred, wsi, N);
  for (int l = 0; l < 2; ++l) {
    agg_kernel<<<(N + 3) / 4, 256, 0, stream>>>(h, offsets, esrc, tmp, N);
    gemm_kernel<H, false, false><<<gemm_grid, 256, 0, stream>>>(
        tmp, wTc + (size_t)l * H * H, b_conv + (size_t)l * H, bn_conv + (size_t)l * 4 * H,
        w_lin + (size_t)(l + 1) * H, b_lin, l + 1, batch, h, node_pred,
        wsi + (size_t)(l + 1) * NGRAPH, N);
  }
  finalize_kernel<<<1, 64, 0, stream>>>(wsi, out);
}

// Round 4
// 343.251 us; speedup vs baseline: 10.8900x; 1.4817x over previous
//
#include <hip/hip_runtime.h>
#include <hip/hip_bf16.h>

#define H 128
#define D_IN 256
#define NGRAPH 8

typedef __attribute__((ext_vector_type(8))) short bf16x8;
typedef __attribute__((ext_vector_type(4))) float f32x4;
typedef __attribute__((ext_vector_type(4))) int i32x4;

// ---- order-preserving float<->unsigned encoding for atomicMax-based segment_max
__device__ __forceinline__ unsigned fenc(float f) {
  unsigned u = __float_as_uint(f);
  return (u & 0x80000000u) ? ~u : (u | 0x80000000u);
}
__device__ __forceinline__ float fdec(unsigned e) {
  unsigned v = (e & 0x80000000u) ? (e & 0x7FFFFFFFu) : ~e;
  return __uint_as_float(v);
}
__device__ __forceinline__ unsigned short f2bf(float f) {  // RNE f32->bf16
  unsigned u = __float_as_uint(f);
  unsigned r = u + 0x7FFFu + ((u >> 16) & 1u);
  return (unsigned short)(r >> 16);
}

__global__ void init_kernel(int* __restrict__ offsets, unsigned* __restrict__ wsi, int n1) {
  int i = blockIdx.x * blockDim.x + threadIdx.x;
  if (i < n1) offsets[i] = 0;
  if (i < 3 * NGRAPH) wsi[i] = 0u;  // 0 < fenc(any finite float)
}

__global__ void count_kernel(const int* __restrict__ dst, int* __restrict__ offsets, int E) {
  int i = blockIdx.x * blockDim.x + threadIdx.x;
  int stride = gridDim.x * blockDim.x;
  for (int e = i; e < E; e += stride) atomicAdd(&offsets[dst[e]], 1);
}

// ---- hierarchical scan: local exclusive scan per 1024-block + block sums
__global__ void __launch_bounds__(1024)
scan_local(int* __restrict__ data, int* __restrict__ bsum, int n) {
  __shared__ int s[1024];
  int tid = threadIdx.x;
  int i = blockIdx.x * 1024 + tid;
  int v = (i < n) ? data[i] : 0;
  s[tid] = v;
  __syncthreads();
  for (int off = 1; off < 1024; off <<= 1) {
    int t = (tid >= off) ? s[tid - off] : 0;
    __syncthreads();
    s[tid] += t;
    __syncthreads();
  }
  if (i < n) data[i] = s[tid] - v;  // exclusive
  if (tid == 1023) bsum[blockIdx.x] = s[1023];
}

// single small block: exclusive scan of nb (<=128) block sums in place
__global__ void __launch_bounds__(128)
scan_bsum(int* __restrict__ bsum, int nb) {
  __shared__ int s[128];
  int tid = threadIdx.x;
  int v = (tid < nb) ? bsum[tid] : 0;
  s[tid] = v;
  __syncthreads();
  for (int off = 1; off < 128; off <<= 1) {
    int t = (tid >= off) ? s[tid - off] : 0;
    __syncthreads();
    s[tid] += t;
    __syncthreads();
  }
  if (tid < nb) bsum[tid] = s[tid] - v;  // exclusive
}

__global__ void __launch_bounds__(1024)
scan_add(int* __restrict__ data, const int* __restrict__ bsum, int* __restrict__ cursor,
         int n, int ncur) {
  int i = blockIdx.x * 1024 + threadIdx.x;
  if (i < n) {
    int v = data[i] + bsum[blockIdx.x];
    data[i] = v;
    if (i < ncur) cursor[i] = v;
  }
}

__global__ void fill_kernel(const int* __restrict__ src, const int* __restrict__ dst,
                            int* __restrict__ cursor, int* __restrict__ esrc, int E) {
  int i = blockIdx.x * blockDim.x + threadIdx.x;
  int stride = gridDim.x * blockDim.x;
  for (int e = i; e < E; e += stride) {
    int d = dst[e];
    int p = atomicAdd(&cursor[d], 1);
    esrc[p] = src[e];
  }
}

// transpose + convert weights to bf16: wT[n][k] = bf16(w[k][n])
__global__ void prep_weights(const float* __restrict__ wf, const float* __restrict__ wcv,
                             unsigned short* __restrict__ wTf, unsigned short* __restrict__ wTc) {
  int i = blockIdx.x * 256 + threadIdx.x;
  if (i < H * D_IN) {
    int n = i >> 8, k = i & 255;
    wTf[i] = f2bf(wf[k * H + n]);
  } else if (i < H * D_IN + 2 * H * H) {
    int j = i - H * D_IN;
    int l = j >> 14, r = j & 16383;
    int n = r >> 7, k = r & 127;
    wTc[j] = f2bf(wcv[l * H * H + k * H + n]);
  }
}

// Fused GEMM [N x K] @ [K x 128] + bias + BN(eval) + ReLU -> h (bf16),
// plus linear head -> node_pred and per-graph segment-max -> wsi.
// 256 threads = 4 waves in 2x2; wave tile 64x64 via mfma 16x16x32 bf16.
template <int K, bool AF32, bool FIRST>
__global__ void __launch_bounds__(256)
gemm_kernel(const void* __restrict__ Ain, const unsigned short* __restrict__ wT,
            const float* __restrict__ bias, const float* __restrict__ bn,
            const float* __restrict__ wlin, const float* __restrict__ blin, int lidx,
            const int* __restrict__ batch, unsigned short* __restrict__ hout,
            float* __restrict__ node_pred, unsigned* __restrict__ wsi, int N) {
  __shared__ char s_a[4][4096];        // per-wave private: A tile [64 rows][64 B], swizzled
  __shared__ unsigned s_wsi[NGRAPH];
  const int tid = threadIdx.x;
  const int wid = tid >> 6, lane = tid & 63;
  const int wr = wid >> 1, wc = wid & 1;
  const int g = lane >> 4, l15 = lane & 15;
  if (tid < NGRAPH) s_wsi[tid] = 0u;
  __syncthreads();

  char* aw = s_a[wid];
  const int growA = blockIdx.x * 128 + wr * 64 + lane;  // this lane's staging row
  f32x4 acc[4][4] = {};

  for (int k0 = 0; k0 < K; k0 += 32) {
    // ---- stage A chunk [64 rows][32 cols] into LDS (bf16, slot-swizzled)
    if (AF32) {
      const float* xr = (const float*)Ain + (size_t)growA * K + k0;
#pragma unroll
      for (int s = 0; s < 4; ++s) {
        float4 u0 = {0, 0, 0, 0}, u1 = {0, 0, 0, 0};
        if (growA < N) {
          u0 = *(const float4*)(xr + s * 8);
          u1 = *(const float4*)(xr + s * 8 + 4);
        }
        union { unsigned short hh[8]; i32x4 q; } pk;
        pk.hh[0] = f2bf(u0.x); pk.hh[1] = f2bf(u0.y); pk.hh[2] = f2bf(u0.z); pk.hh[3] = f2bf(u0.w);
        pk.hh[4] = f2bf(u1.x); pk.hh[5] = f2bf(u1.y); pk.hh[6] = f2bf(u1.z); pk.hh[7] = f2bf(u1.w);
        *(i32x4*)(aw + lane * 64 + ((s ^ (lane & 3)) << 4)) = pk.q;
      }
    } else {
      const unsigned short* tr = (const unsigned short*)Ain + (size_t)growA * K + k0;
#pragma unroll
      for (int s = 0; s < 4; ++s) {
        i32x4 q = {0, 0, 0, 0};
        if (growA < N) q = *(const i32x4*)(tr + s * 8);
        *(i32x4*)(aw + lane * 64 + ((s ^ (lane & 3)) << 4)) = q;
      }
    }
    // ---- fragments + MFMA (DS ops are in-order within a wave; LDS is wave-private)
    bf16x8 af[4], bfr[4];
#pragma unroll
    for (int m = 0; m < 4; ++m) {
      int r = m * 16 + l15;
      af[m] = *(bf16x8*)(aw + r * 64 + ((g ^ (r & 3)) << 4));
    }
#pragma unroll
    for (int n = 0; n < 4; ++n) {
      int c = wc * 64 + n * 16 + l15;
      bfr[n] = *(const bf16x8*)(wT + (size_t)c * K + k0 + g * 8);
    }
#pragma unroll
    for (int m = 0; m < 4; ++m)
#pragma unroll
      for (int n = 0; n < 4; ++n)
        acc[m][n] = __builtin_amdgcn_mfma_f32_16x16x32_bf16(af[m], bfr[n], acc[m][n], 0, 0, 0);
  }

  // ---- epilogue: bias+BN+ReLU folded to hv = acc*sc + sh
  float sc[4], sh[4];
#pragma unroll
  for (int n = 0; n < 4; ++n) {
    int c = wc * 64 + n * 16 + l15;
    float gam = bn[c], bet = bn[H + c], mu = bn[2 * H + c], va = bn[3 * H + c];
    float rs = rsqrtf(va + 1e-5f);
    sc[n] = gam * rs;
    sh[n] = (bias[c] - mu) * gam * rs + bet;
  }

#pragma unroll
  for (int m = 0; m < 4; ++m) {
    // write this wave's 16x64 output tile (bf16) into its LDS region
#pragma unroll
    for (int n = 0; n < 4; ++n)
#pragma unroll
      for (int j = 0; j < 4; ++j) {
        float hv = fmaxf(acc[m][n][j] * sc[n] + sh[n], 0.f);
        int rr = g * 4 + j;
        *(unsigned short*)(aw + rr * 128 + (n * 16 + l15) * 2) = f2bf(hv);
      }
    // coalesced bf16 h store (16 rows x 64 cols per wave)
    int grb = blockIdx.x * 128 + wr * 64 + m * 16;
#pragma unroll
    for (int it = 0; it < 2; ++it) {
      int bo = lane * 16 + it * 1024;
      int r16 = bo >> 7, inrow = bo & 127;
      if (grb + r16 < N)
        *(i32x4*)((char*)hout + (size_t)(grb + r16) * 256 + wc * 128 + inrow) =
            *(i32x4*)(aw + bo);
    }
    __syncthreads();
    // head: 32 rows (both wr halves) x 128 cols; 8 threads per row
    {
      int rid = tid >> 3, oct = tid & 7;
      int wr2 = rid >> 4, r16 = rid & 15;
      const char* reg = s_a[wr2 * 2 + (oct >> 2)];
      int lb = r16 * 128 + (oct & 3) * 32;
      float sum = 0.f;
#pragma unroll
      for (int half = 0; half < 2; ++half) {
        union { i32x4 q; unsigned short hh[8]; } t;
        t.q = *(const i32x4*)(reg + lb + half * 16);
#pragma unroll
        for (int i = 0; i < 8; ++i) {
          float hv = __uint_as_float(((unsigned)t.hh[i]) << 16);
          sum += hv * wlin[oct * 16 + half * 8 + i];
        }
      }
      sum += __shfl_xor(sum, 1);
      sum += __shfl_xor(sum, 2);
      sum += __shfl_xor(sum, 4);
      int grh = blockIdx.x * 128 + wr2 * 64 + m * 16 + r16;
      if (oct == 0 && grh < N) {
        float np = sum + blin[lidx];
        if (FIRST) node_pred[grh] = np; else node_pred[grh] += np;
        atomicMax(&s_wsi[batch[grh]], fenc(np));
      }
    }
    __syncthreads();
  }
  if (tid < NGRAPH && s_wsi[tid] != 0u) atomicMax(&wsi[tid], s_wsi[tid]);
}

// tmp[i] = h[i] + sum_{j in-edges} h[src_j]   (bf16 storage, f32 accumulate)
__global__ void __launch_bounds__(256)
agg_kernel(const unsigned short* __restrict__ h, const int* __restrict__ offsets,
           const int* __restrict__ esrc, unsigned short* __restrict__ tmp, int n) {
  int node = blockIdx.x * 4 + (threadIdx.x >> 6);
  if (node >= n) return;
  int lane = threadIdx.x & 63;  // 2 features per lane
  const unsigned* hw = (const unsigned*)h;
  size_t base = (size_t)node * (H / 2) + lane;
  unsigned u = hw[base];
  float a0 = __uint_as_float((u & 0xFFFFu) << 16);
  float a1 = __uint_as_float(u & 0xFFFF0000u);
  int s = offsets[node], e = offsets[node + 1];
  for (int j = s; j < e; ++j) {
    int sj = esrc[j];
    unsigned v2 = hw[(size_t)sj * (H / 2) + lane];
    a0 += __uint_as_float((v2 & 0xFFFFu) << 16);
    a1 += __uint_as_float(v2 & 0xFFFF0000u);
  }
  unsigned r = ((unsigned)f2bf(a1) << 16) | (unsigned)f2bf(a0);
  ((unsigned*)tmp)[base] = r;
}

__global__ void finalize_kernel(const unsigned* __restrict__ wsi, float* __restrict__ out) {
  int g = threadIdx.x;
  if (g < NGRAPH) out[g] = fdec(wsi[g]) + fdec(wsi[NGRAPH + g]) + fdec(wsi[2 * NGRAPH + g]);
}

extern "C" void kernel_launch(void* const* d_in, const int* in_sizes, int n_in,
                              void* d_out, int out_size, void* d_ws, size_t ws_size,
                              hipStream_t stream) {
  const float* x        = (const float*)d_in[0];
  const int*   ei       = (const int*)d_in[1];
  const int*   batch    = (const int*)d_in[2];
  const float* w_first  = (const float*)d_in[3];
  const float* b_first  = (const float*)d_in[4];
  const float* bn_first = (const float*)d_in[5];
  const float* w_conv   = (const float*)d_in[6];
  const float* b_conv   = (const float*)d_in[7];
  const float* bn_conv  = (const float*)d_in[8];
  const float* w_lin    = (const float*)d_in[9];
  const float* b_lin    = (const float*)d_in[10];
  float* out = (float*)d_out;

  const int N = in_sizes[0] / D_IN;
  const int E = in_sizes[1] / 2;
  const int* src = ei;
  const int* dst = ei + E;

  char* ws = (char*)d_ws;
  unsigned short* h   = (unsigned short*)ws;            // N*H bf16
  unsigned short* tmp = h + (size_t)N * H;              // N*H bf16
  unsigned short* wTf = tmp + (size_t)N * H;            // 128*256 bf16 (w_first^T)
  unsigned short* wTc = wTf + H * D_IN;                 // 2*128*128 bf16 (w_conv^T)
  int* offsets = (int*)(wTc + 2 * H * H);
  int* cursor  = offsets + (N + 1);
  int* esrc    = cursor + N;
  int* bsum    = esrc + E;                              // scan block sums (<=128)
  unsigned* wsi = (unsigned*)(bsum + 128);
  float* node_pred = out + NGRAPH;

  const int gemm_grid = (N + 127) / 128;
  const int nscan = N + 1;
  const int nb = (nscan + 1023) / 1024;                 // 98 for N=100000 (must be <=128)

  init_kernel<<<(N + 256) / 256, 256, 0, stream>>>(offsets, wsi, N + 1);
  count_kernel<<<1024, 256, 0, stream>>>(dst, offsets, E);
  scan_local<<<nb, 1024, 0, stream>>>(offsets, bsum, nscan);
  scan_bsum<<<1, 128, 0, stream>>>(bsum, nb);
  scan_add<<<nb, 1024, 0, stream>>>(offsets, bsum, cursor, nscan, N);
  fill_kernel<<<1024, 256, 0, stream>>>(src, dst, cursor, esrc, E);
  prep_weights<<<256, 256, 0, stream>>>(w_first, w_conv, wTf, wTc);

  gemm_kernel<D_IN, true, true><<<gemm_grid, 256, 0, stream>>>(
      x, wTf, b_first, bn_first, w_lin, b_lin, 0, batch, h, node_pred, wsi, N);
  for (int l = 0; l < 2; ++l) {
    agg_kernel<<<(N + 3) / 4, 256, 0, stream>>>(h, offsets, esrc, tmp, N);
    gemm_kernel<H, false, false><<<gemm_grid, 256, 0, stream>>>(
        tmp, wTc + (size_t)l * H * H, b_conv + (size_t)l * H, bn_conv + (size_t)l * 4 * H,
        w_lin + (size_t)(l + 1) * H, b_lin, l + 1, batch, h, node_pred,
        wsi + (size_t)(l + 1) * NGRAPH, N);
  }
  finalize_kernel<<<1, 64, 0, stream>>>(wsi, out);
}

// Round 5
// 280.483 us; speedup vs baseline: 13.3270x; 1.2238x over previous
//
#include <hip/hip_runtime.h>
#include <hip/hip_bf16.h>

#define H 128
#define D_IN 256
#define NGRAPH 8

typedef __attribute__((ext_vector_type(8))) short bf16x8;
typedef __attribute__((ext_vector_type(4))) float f32x4;
typedef __attribute__((ext_vector_type(4))) int i32x4;

// ---- order-preserving float<->unsigned encoding for atomicMax-based segment_max
__device__ __forceinline__ unsigned fenc(float f) {
  unsigned u = __float_as_uint(f);
  return (u & 0x80000000u) ? ~u : (u | 0x80000000u);
}
__device__ __forceinline__ float fdec(unsigned e) {
  unsigned v = (e & 0x80000000u) ? (e & 0x7FFFFFFFu) : ~e;
  return __uint_as_float(v);
}
__device__ __forceinline__ unsigned short f2bf(float f) {  // RNE f32->bf16
  unsigned u = __float_as_uint(f);
  unsigned r = u + 0x7FFFu + ((u >> 16) & 1u);
  return (unsigned short)(r >> 16);
}

__global__ void init_kernel(int* __restrict__ offsets, unsigned* __restrict__ wsi, int n1) {
  int i = blockIdx.x * blockDim.x + threadIdx.x;
  if (i < n1) offsets[i] = 0;
  if (i < 3 * NGRAPH) wsi[i] = 0u;  // 0 < fenc(any finite float)
}

__global__ void count_kernel(const int* __restrict__ dst, int* __restrict__ offsets, int E) {
  int i = blockIdx.x * blockDim.x + threadIdx.x;
  int stride = gridDim.x * blockDim.x;
  for (int e = i; e < E; e += stride) atomicAdd(&offsets[dst[e]], 1);
}

// ---- hierarchical scan: local exclusive scan per 1024-block + block sums
__global__ void __launch_bounds__(1024)
scan_local(int* __restrict__ data, int* __restrict__ bsum, int n) {
  __shared__ int s[1024];
  int tid = threadIdx.x;
  int i = blockIdx.x * 1024 + tid;
  int v = (i < n) ? data[i] : 0;
  s[tid] = v;
  __syncthreads();
  for (int off = 1; off < 1024; off <<= 1) {
    int t = (tid >= off) ? s[tid - off] : 0;
    __syncthreads();
    s[tid] += t;
    __syncthreads();
  }
  if (i < n) data[i] = s[tid] - v;  // exclusive
  if (tid == 1023) bsum[blockIdx.x] = s[1023];
}

__global__ void __launch_bounds__(128)
scan_bsum(int* __restrict__ bsum, int nb) {
  __shared__ int s[128];
  int tid = threadIdx.x;
  int v = (tid < nb) ? bsum[tid] : 0;
  s[tid] = v;
  __syncthreads();
  for (int off = 1; off < 128; off <<= 1) {
    int t = (tid >= off) ? s[tid - off] : 0;
    __syncthreads();
    s[tid] += t;
    __syncthreads();
  }
  if (tid < nb) bsum[tid] = s[tid] - v;  // exclusive
}

__global__ void __launch_bounds__(1024)
scan_add(int* __restrict__ data, const int* __restrict__ bsum, int* __restrict__ cursor,
         int n, int ncur) {
  int i = blockIdx.x * 1024 + threadIdx.x;
  if (i < n) {
    int v = data[i] + bsum[blockIdx.x];
    data[i] = v;
    if (i < ncur) cursor[i] = v;
  }
}

__global__ void fill_kernel(const int* __restrict__ src, const int* __restrict__ dst,
                            int* __restrict__ cursor, int* __restrict__ esrc, int E) {
  int i = blockIdx.x * blockDim.x + threadIdx.x;
  int stride = gridDim.x * blockDim.x;
  for (int e = i; e < E; e += stride) {
    int d = dst[e];
    int p = atomicAdd(&cursor[d], 1);
    esrc[p] = src[e];
  }
}

// transpose + convert weights to bf16: wT[n][k] = bf16(w[k][n])
__global__ void prep_weights(const float* __restrict__ wf, const float* __restrict__ wcv,
                             unsigned short* __restrict__ wTf, unsigned short* __restrict__ wTc) {
  int i = blockIdx.x * 256 + threadIdx.x;
  if (i < H * D_IN) {
    int n = i >> 8, k = i & 255;
    wTf[i] = f2bf(wf[k * H + n]);
  } else if (i < H * D_IN + 2 * H * H) {
    int j = i - H * D_IN;
    int l = j >> 14, r = j & 16383;
    int n = r >> 7, k = r & 127;
    wTc[j] = f2bf(wcv[l * H * H + k * H + n]);
  }
}

// Fused GEMM [N x K] @ [K x 128] + bias + BN(eval) + ReLU -> h (bf16),
// plus linear head -> node_pred and per-graph segment-max -> wsi.
// 256 threads = 4 waves in 2x2; wave tile 64x64 via mfma 16x16x32 bf16.
// A fragments loaded DIRECTLY from global (no LDS staging, no K-loop barriers).
template <int K, bool AF32, bool FIRST>
__global__ void __launch_bounds__(256)
gemm_kernel(const void* __restrict__ Ain, const unsigned short* __restrict__ wT,
            const float* __restrict__ bias, const float* __restrict__ bn,
            const float* __restrict__ wlin, const float* __restrict__ blin, int lidx,
            const int* __restrict__ batch, unsigned short* __restrict__ hout,
            float* __restrict__ node_pred, unsigned* __restrict__ wsi, int N) {
  __shared__ char s_tile[4][2048];     // per-wave h-store staging (16 rows x 64 cols bf16)
  __shared__ float s_head[128][2];     // per-row linear-head partials (wc halves)
  __shared__ unsigned s_wsi[NGRAPH];
  const int tid = threadIdx.x;
  const int wid = tid >> 6, lane = tid & 63;
  const int wr = wid >> 1, wc = wid & 1;
  const int g = lane >> 4, l15 = lane & 15;
  if (tid < NGRAPH) s_wsi[tid] = 0u;
  __syncthreads();

  const int row0 = blockIdx.x * 128 + wr * 64;
  f32x4 acc[4][4] = {};

#pragma unroll
  for (int k0 = 0; k0 < K; k0 += 32) {
    bf16x8 af[4];
    if (AF32) {
      const float* A = (const float*)Ain;
#pragma unroll
      for (int m = 0; m < 4; ++m) {
        int r = row0 + m * 16 + l15;
        r = (r < N) ? r : (N - 1);  // clamp: always-valid load, result discarded on store
        const float* p = A + (size_t)r * K + k0 + g * 8;
        float4 u0 = *(const float4*)p;
        float4 u1 = *(const float4*)(p + 4);
        union { unsigned short hh[8]; bf16x8 v; } pk;
        pk.hh[0] = f2bf(u0.x); pk.hh[1] = f2bf(u0.y); pk.hh[2] = f2bf(u0.z); pk.hh[3] = f2bf(u0.w);
        pk.hh[4] = f2bf(u1.x); pk.hh[5] = f2bf(u1.y); pk.hh[6] = f2bf(u1.z); pk.hh[7] = f2bf(u1.w);
        af[m] = pk.v;
      }
    } else {
      const unsigned short* A = (const unsigned short*)Ain;
#pragma unroll
      for (int m = 0; m < 4; ++m) {
        int r = row0 + m * 16 + l15;
        r = (r < N) ? r : (N - 1);
        i32x4 q = *(const i32x4*)(A + (size_t)r * K + k0 + g * 8);
        af[m] = *(bf16x8*)&q;
      }
    }
    bf16x8 bfr[4];
#pragma unroll
    for (int n = 0; n < 4; ++n) {
      int c = wc * 64 + n * 16 + l15;
      bfr[n] = *(const bf16x8*)(wT + (size_t)c * K + k0 + g * 8);
    }
#pragma unroll
    for (int m = 0; m < 4; ++m)
#pragma unroll
      for (int n = 0; n < 4; ++n)
        acc[m][n] = __builtin_amdgcn_mfma_f32_16x16x32_bf16(af[m], bfr[n], acc[m][n], 0, 0, 0);
  }

  // ---- epilogue: bias+BN+ReLU folded to hv = acc*sc + sh
  float sc[4], sh[4], wl[4];
#pragma unroll
  for (int n = 0; n < 4; ++n) {
    int c = wc * 64 + n * 16 + l15;
    float gam = bn[c], bet = bn[H + c], mu = bn[2 * H + c], va = bn[3 * H + c];
    float rs = rsqrtf(va + 1e-5f);
    sc[n] = gam * rs;
    sh[n] = (bias[c] - mu) * gam * rs + bet;
    wl[n] = wlin[c];
  }

  char* aw = s_tile[wid];
#pragma unroll
  for (int m = 0; m < 4; ++m) {
    float pj[4] = {0.f, 0.f, 0.f, 0.f};
#pragma unroll
    for (int n = 0; n < 4; ++n)
#pragma unroll
      for (int j = 0; j < 4; ++j) {
        float hv = fmaxf(acc[m][n][j] * sc[n] + sh[n], 0.f);
        pj[j] += hv * wl[n];
        *(unsigned short*)(aw + (g * 4 + j) * 128 + (n * 16 + l15) * 2) = f2bf(hv);
      }
    // head partial: reduce across the 16 lanes (l15) of this g-group
#pragma unroll
    for (int j = 0; j < 4; ++j) {
      pj[j] += __shfl_xor(pj[j], 1);
      pj[j] += __shfl_xor(pj[j], 2);
      pj[j] += __shfl_xor(pj[j], 4);
      pj[j] += __shfl_xor(pj[j], 8);
    }
    if (l15 == 0) {
#pragma unroll
      for (int j = 0; j < 4; ++j)
        s_head[wr * 64 + m * 16 + g * 4 + j][wc] = pj[j];
    }
    // coalesced bf16 h store (wave-private LDS bounce; DS in-order, no barrier)
    int grb = row0 + m * 16;
#pragma unroll
    for (int it = 0; it < 2; ++it) {
      int bo = lane * 16 + it * 1024;
      int r16 = bo >> 7, inrow = bo & 127;
      if (grb + r16 < N)
        *(i32x4*)((char*)hout + (size_t)(grb + r16) * 256 + wc * 128 + inrow) =
            *(i32x4*)(aw + bo);
    }
  }
  __syncthreads();
  // finish head: one thread per block-row
  if (tid < 128) {
    int grh = blockIdx.x * 128 + tid;
    if (grh < N) {
      float np = s_head[tid][0] + s_head[tid][1] + blin[lidx];
      if (FIRST) node_pred[grh] = np; else node_pred[grh] += np;
      atomicMax(&s_wsi[batch[grh]], fenc(np));
    }
  }
  __syncthreads();
  if (tid < NGRAPH && s_wsi[tid] != 0u) atomicMax(&wsi[tid], s_wsi[tid]);
}

// tmp[i] = h[i] + sum_{j in-edges} h[src_j]   (bf16 storage, f32 accumulate)
// 4-wide index prefetch: 4 uniform index loads + 4 independent gathers in flight.
__global__ void __launch_bounds__(256)
agg_kernel(const unsigned short* __restrict__ h, const int* __restrict__ offsets,
           const int* __restrict__ esrc, unsigned short* __restrict__ tmp, int n) {
  int node = blockIdx.x * 4 + (threadIdx.x >> 6);
  if (node >= n) return;
  int lane = threadIdx.x & 63;  // 2 features per lane
  const unsigned* hw = (const unsigned*)h;
  size_t base = (size_t)node * (H / 2) + lane;
  unsigned u = hw[base];
  float a0 = __uint_as_float((u & 0xFFFFu) << 16);
  float a1 = __uint_as_float(u & 0xFFFF0000u);
  int s = offsets[node], e = offsets[node + 1];
  int j = s;
  for (; j + 4 <= e; j += 4) {
    int i0 = esrc[j], i1 = esrc[j + 1], i2 = esrc[j + 2], i3 = esrc[j + 3];
    unsigned v0 = hw[(size_t)i0 * (H / 2) + lane];
    unsigned v1 = hw[(size_t)i1 * (H / 2) + lane];
    unsigned v2 = hw[(size_t)i2 * (H / 2) + lane];
    unsigned v3 = hw[(size_t)i3 * (H / 2) + lane];
    a0 += __uint_as_float((v0 & 0xFFFFu) << 16) + __uint_as_float((v1 & 0xFFFFu) << 16) +
          __uint_as_float((v2 & 0xFFFFu) << 16) + __uint_as_float((v3 & 0xFFFFu) << 16);
    a1 += __uint_as_float(v0 & 0xFFFF0000u) + __uint_as_float(v1 & 0xFFFF0000u) +
          __uint_as_float(v2 & 0xFFFF0000u) + __uint_as_float(v3 & 0xFFFF0000u);
  }
  for (; j < e; ++j) {
    unsigned v2 = hw[(size_t)esrc[j] * (H / 2) + lane];
    a0 += __uint_as_float((v2 & 0xFFFFu) << 16);
    a1 += __uint_as_float(v2 & 0xFFFF0000u);
  }
  unsigned r = ((unsigned)f2bf(a1) << 16) | (unsigned)f2bf(a0);
  ((unsigned*)tmp)[base] = r;
}

__global__ void finalize_kernel(const unsigned* __restrict__ wsi, float* __restrict__ out) {
  int g = threadIdx.x;
  if (g < NGRAPH) out[g] = fdec(wsi[g]) + fdec(wsi[NGRAPH + g]) + fdec(wsi[2 * NGRAPH + g]);
}

extern "C" void kernel_launch(void* const* d_in, const int* in_sizes, int n_in,
                              void* d_out, int out_size, void* d_ws, size_t ws_size,
                              hipStream_t stream) {
  const float* x        = (const float*)d_in[0];
  const int*   ei       = (const int*)d_in[1];
  const int*   batch    = (const int*)d_in[2];
  const float* w_first  = (const float*)d_in[3];
  const float* b_first  = (const float*)d_in[4];
  const float* bn_first = (const float*)d_in[5];
  const float* w_conv   = (const float*)d_in[6];
  const float* b_conv   = (const float*)d_in[7];
  const float* bn_conv  = (const float*)d_in[8];
  const float* w_lin    = (const float*)d_in[9];
  const float* b_lin    = (const float*)d_in[10];
  float* out = (float*)d_out;

  const int N = in_sizes[0] / D_IN;
  const int E = in_sizes[1] / 2;
  const int* src = ei;
  const int* dst = ei + E;

  char* ws = (char*)d_ws;
  unsigned short* h   = (unsigned short*)ws;            // N*H bf16
  unsigned short* tmp = h + (size_t)N * H;              // N*H bf16
  unsigned short* wTf = tmp + (size_t)N * H;            // 128*256 bf16 (w_first^T)
  unsigned short* wTc = wTf + H * D_IN;                 // 2*128*128 bf16 (w_conv^T)
  int* offsets = (int*)(wTc + 2 * H * H);
  int* cursor  = offsets + (N + 1);
  int* esrc    = cursor + N;
  int* bsum    = esrc + E;                              // scan block sums (<=128)
  unsigned* wsi = (unsigned*)(bsum + 128);
  float* node_pred = out + NGRAPH;

  const int gemm_grid = (N + 127) / 128;
  const int nscan = N + 1;
  const int nb = (nscan + 1023) / 1024;                 // 98 for N=100000 (must be <=128)

  init_kernel<<<(N + 256) / 256, 256, 0, stream>>>(offsets, wsi, N + 1);
  count_kernel<<<1024, 256, 0, stream>>>(dst, offsets, E);
  scan_local<<<nb, 1024, 0, stream>>>(offsets, bsum, nscan);
  scan_bsum<<<1, 128, 0, stream>>>(bsum, nb);
  scan_add<<<nb, 1024, 0, stream>>>(offsets, bsum, cursor, nscan, N);
  fill_kernel<<<1024, 256, 0, stream>>>(src, dst, cursor, esrc, E);
  prep_weights<<<256, 256, 0, stream>>>(w_first, w_conv, wTf, wTc);

  gemm_kernel<D_IN, true, true><<<gemm_grid, 256, 0, stream>>>(
      x, wTf, b_first, bn_first, w_lin, b_lin, 0, batch, h, node_pred, wsi, N);
  for (int l = 0; l < 2; ++l) {
    agg_kernel<<<(N + 3) / 4, 256, 0, stream>>>(h, offsets, esrc, tmp, N);
    gemm_kernel<H, false, false><<<gemm_grid, 256, 0, stream>>>(
        tmp, wTc + (size_t)l * H * H, b_conv + (size_t)l * H, bn_conv + (size_t)l * 4 * H,
        w_lin + (size_t)(l + 1) * H, b_lin, l + 1, batch, h, node_pred,
        wsi + (size_t)(l + 1) * NGRAPH, N);
  }
  finalize_kernel<<<1, 64, 0, stream>>>(wsi, out);
}

// Round 6
// 278.944 us; speedup vs baseline: 13.4006x; 1.0055x over previous
//
#include <hip/hip_runtime.h>
#include <hip/hip_bf16.h>

#define H 128
#define D_IN 256
#define NGRAPH 8

typedef __attribute__((ext_vector_type(8))) short bf16x8;
typedef __attribute__((ext_vector_type(4))) float f32x4;
typedef __attribute__((ext_vector_type(4))) int i32x4;

// ---- order-preserving float<->unsigned encoding for atomicMax-based segment_max
__device__ __forceinline__ unsigned fenc(float f) {
  unsigned u = __float_as_uint(f);
  return (u & 0x80000000u) ? ~u : (u | 0x80000000u);
}
__device__ __forceinline__ float fdec(unsigned e) {
  unsigned v = (e & 0x80000000u) ? (e & 0x7FFFFFFFu) : ~e;
  return __uint_as_float(v);
}
__device__ __forceinline__ unsigned short f2bf(float f) {  // RNE f32->bf16
  unsigned u = __float_as_uint(f);
  unsigned r = u + 0x7FFFu + ((u >> 16) & 1u);
  return (unsigned short)(r >> 16);
}

__global__ void init_kernel(int* __restrict__ offsets, unsigned* __restrict__ wsi, int n1) {
  int i = blockIdx.x * blockDim.x + threadIdx.x;
  if (i < n1) offsets[i] = 0;
  if (i < 3 * NGRAPH) wsi[i] = 0u;  // 0 < fenc(any finite float)
}

__global__ void count_kernel(const int* __restrict__ dst, int* __restrict__ offsets, int E) {
  int i = blockIdx.x * blockDim.x + threadIdx.x;
  int stride = gridDim.x * blockDim.x;
  for (int e = i; e < E; e += stride) atomicAdd(&offsets[dst[e]], 1);
}

// ---- hierarchical scan
__global__ void __launch_bounds__(1024)
scan_local(int* __restrict__ data, int* __restrict__ bsum, int n) {
  __shared__ int s[1024];
  int tid = threadIdx.x;
  int i = blockIdx.x * 1024 + tid;
  int v = (i < n) ? data[i] : 0;
  s[tid] = v;
  __syncthreads();
  for (int off = 1; off < 1024; off <<= 1) {
    int t = (tid >= off) ? s[tid - off] : 0;
    __syncthreads();
    s[tid] += t;
    __syncthreads();
  }
  if (i < n) data[i] = s[tid] - v;  // exclusive
  if (tid == 1023) bsum[blockIdx.x] = s[1023];
}

__global__ void __launch_bounds__(128)
scan_bsum(int* __restrict__ bsum, int nb) {
  __shared__ int s[128];
  int tid = threadIdx.x;
  int v = (tid < nb) ? bsum[tid] : 0;
  s[tid] = v;
  __syncthreads();
  for (int off = 1; off < 128; off <<= 1) {
    int t = (tid >= off) ? s[tid - off] : 0;
    __syncthreads();
    s[tid] += t;
    __syncthreads();
  }
  if (tid < nb) bsum[tid] = s[tid] - v;  // exclusive
}

__global__ void __launch_bounds__(1024)
scan_add(int* __restrict__ data, const int* __restrict__ bsum, int* __restrict__ cursor,
         int n, int ncur) {
  int i = blockIdx.x * 1024 + threadIdx.x;
  if (i < n) {
    int v = data[i] + bsum[blockIdx.x];
    data[i] = v;
    if (i < ncur) cursor[i] = v;
  }
}

__global__ void fill_kernel(const int* __restrict__ src, const int* __restrict__ dst,
                            int* __restrict__ cursor, int* __restrict__ esrc, int E) {
  int i = blockIdx.x * blockDim.x + threadIdx.x;
  int stride = gridDim.x * blockDim.x;
  for (int e = i; e < E; e += stride) {
    int d = dst[e];
    int p = atomicAdd(&cursor[d], 1);
    esrc[p] = src[e];
  }
}

// transpose + convert weights to bf16: wT[n][k] = bf16(w[k][n])
__global__ void prep_weights(const float* __restrict__ wf, const float* __restrict__ wcv,
                             unsigned short* __restrict__ wTf, unsigned short* __restrict__ wTc) {
  int i = blockIdx.x * 256 + threadIdx.x;
  if (i < H * D_IN) {
    int n = i >> 8, k = i & 255;
    wTf[i] = f2bf(wf[k * H + n]);
  } else if (i < H * D_IN + 2 * H * H) {
    int j = i - H * D_IN;
    int l = j >> 14, r = j & 16383;
    int n = r >> 7, k = r & 127;
    wTc[j] = f2bf(wcv[l * H * H + k * H + n]);
  }
}

// ---- pipeline stages (per k-step fragments held in registers)
struct af32_stage { float4 u0[4], u1[4]; };  // f32 A rows, pre-conversion
struct abf_stage  { i32x4 q[4]; };           // bf16 A fragments
struct b_stage    { i32x4 q[4]; };           // bf16 B fragments

__device__ __forceinline__ void issueA_f32(af32_stage& st, const char* const aptr[4], int s) {
#pragma unroll
  for (int m = 0; m < 4; ++m) {
    st.u0[m] = *(const float4*)(aptr[m] + s * 128);
    st.u1[m] = *(const float4*)(aptr[m] + s * 128 + 16);
  }
}
__device__ __forceinline__ void issueA_bf(abf_stage& st, const char* const aptr[4], int s) {
#pragma unroll
  for (int m = 0; m < 4; ++m) st.q[m] = *(const i32x4*)(aptr[m] + s * 64);
}
__device__ __forceinline__ void issueB(b_stage& st, const unsigned short* const bptr[4], int s) {
#pragma unroll
  for (int n = 0; n < 4; ++n) st.q[n] = *(const i32x4*)(bptr[n] + s * 32);
}
__device__ __forceinline__ void consume_f32(const af32_stage& st, const b_stage& bs,
                                            f32x4 (&acc)[4][4]) {
  bf16x8 af[4];
#pragma unroll
  for (int m = 0; m < 4; ++m) {
    union { unsigned short hh[8]; bf16x8 v; } pk;
    pk.hh[0] = f2bf(st.u0[m].x); pk.hh[1] = f2bf(st.u0[m].y);
    pk.hh[2] = f2bf(st.u0[m].z); pk.hh[3] = f2bf(st.u0[m].w);
    pk.hh[4] = f2bf(st.u1[m].x); pk.hh[5] = f2bf(st.u1[m].y);
    pk.hh[6] = f2bf(st.u1[m].z); pk.hh[7] = f2bf(st.u1[m].w);
    af[m] = pk.v;
  }
#pragma unroll
  for (int m = 0; m < 4; ++m)
#pragma unroll
    for (int n = 0; n < 4; ++n)
      acc[m][n] = __builtin_amdgcn_mfma_f32_16x16x32_bf16(af[m], *(const bf16x8*)&bs.q[n],
                                                          acc[m][n], 0, 0, 0);
}
__device__ __forceinline__ void consume_bf(const abf_stage& st, const b_stage& bs,
                                           f32x4 (&acc)[4][4]) {
#pragma unroll
  for (int m = 0; m < 4; ++m)
#pragma unroll
    for (int n = 0; n < 4; ++n)
      acc[m][n] = __builtin_amdgcn_mfma_f32_16x16x32_bf16(*(const bf16x8*)&st.q[m],
                                                          *(const bf16x8*)&bs.q[n],
                                                          acc[m][n], 0, 0, 0);
}

// Fused GEMM [N x K] @ [K x 128] + bias + BN(eval) + ReLU -> h (bf16),
// plus linear head -> node_pred and per-graph segment-max -> wsi.
// 4 waves in 2x2; wave tile 64x64; register-software-pipelined A/B loads:
//   K=128 (bf16 A): ALL 4 k-steps prefetched (32 loads in flight);
//   K=256 (f32 A):  2-deep rotating pipeline (~24 loads in flight).
// __launch_bounds__(256,2): allow up to 256 VGPR (occupancy traded for MLP).
template <int K, bool AF32, bool FIRST>
__global__ void __launch_bounds__(256, 2)
gemm_kernel(const void* __restrict__ Ain, const unsigned short* __restrict__ wT,
            const float* __restrict__ bias, const float* __restrict__ bn,
            const float* __restrict__ wlin, const float* __restrict__ blin, int lidx,
            const int* __restrict__ batch, unsigned short* __restrict__ hout,
            float* __restrict__ node_pred, unsigned* __restrict__ wsi, int N) {
  __shared__ char s_tile[4][2048];     // per-wave h-store staging (16 rows x 64 cols bf16)
  __shared__ float s_head[128][2];     // per-row linear-head partials (wc halves)
  __shared__ unsigned s_wsi[NGRAPH];
  const int tid = threadIdx.x;
  const int wid = tid >> 6, lane = tid & 63;
  const int wr = wid >> 1, wc = wid & 1;
  const int g = lane >> 4, l15 = lane & 15;
  if (tid < NGRAPH) s_wsi[tid] = 0u;
  __syncthreads();

  const int row0 = blockIdx.x * 128 + wr * 64;
  f32x4 acc[4][4] = {};

  // per-m row base pointers (clamped rows: always-valid loads, result masked on store)
  const char* aptr[4];
#pragma unroll
  for (int m = 0; m < 4; ++m) {
    int r = row0 + m * 16 + l15;
    r = (r < N) ? r : (N - 1);
    aptr[m] = (const char*)Ain + (size_t)r * K * (AF32 ? 4 : 2) + g * (AF32 ? 32 : 16);
  }
  const unsigned short* bptr[4];
#pragma unroll
  for (int n = 0; n < 4; ++n) {
    int c = wc * 64 + n * 16 + l15;
    bptr[n] = wT + (size_t)c * K + g * 8;
  }

  if constexpr (!AF32) {
    // K must be 128: full prefetch of 4 k-steps
    abf_stage a0, a1, a2, a3;
    b_stage b0, b1, b2, b3;
    issueA_bf(a0, aptr, 0); issueA_bf(a1, aptr, 1);
    issueA_bf(a2, aptr, 2); issueA_bf(a3, aptr, 3);
    issueB(b0, bptr, 0); issueB(b1, bptr, 1);
    issueB(b2, bptr, 2); issueB(b3, bptr, 3);
    consume_bf(a0, b0, acc); consume_bf(a1, b1, acc);
    consume_bf(a2, b2, acc); consume_bf(a3, b3, acc);
  } else {
    // K must be 256: 2-deep rotating pipeline over 8 k-steps
    af32_stage a0, a1;
    b_stage b0, b1;
    issueA_f32(a0, aptr, 0); issueB(b0, bptr, 0);
    issueA_f32(a1, aptr, 1); issueB(b1, bptr, 1);
    consume_f32(a0, b0, acc); issueA_f32(a0, aptr, 2); issueB(b0, bptr, 2);
    consume_f32(a1, b1, acc); issueA_f32(a1, aptr, 3); issueB(b1, bptr, 3);
    consume_f32(a0, b0, acc); issueA_f32(a0, aptr, 4); issueB(b0, bptr, 4);
    consume_f32(a1, b1, acc); issueA_f32(a1, aptr, 5); issueB(b1, bptr, 5);
    consume_f32(a0, b0, acc); issueA_f32(a0, aptr, 6); issueB(b0, bptr, 6);
    consume_f32(a1, b1, acc); issueA_f32(a1, aptr, 7); issueB(b1, bptr, 7);
    consume_f32(a0, b0, acc);
    consume_f32(a1, b1, acc);
  }

  // ---- epilogue: bias+BN+ReLU folded to hv = acc*sc + sh
  float sc[4], sh[4], wl[4];
#pragma unroll
  for (int n = 0; n < 4; ++n) {
    int c = wc * 64 + n * 16 + l15;
    float gam = bn[c], bet = bn[H + c], mu = bn[2 * H + c], va = bn[3 * H + c];
    float rs = rsqrtf(va + 1e-5f);
    sc[n] = gam * rs;
    sh[n] = (bias[c] - mu) * gam * rs + bet;
    wl[n] = wlin[c];
  }

  char* aw = s_tile[wid];
#pragma unroll
  for (int m = 0; m < 4; ++m) {
    float pj[4] = {0.f, 0.f, 0.f, 0.f};
#pragma unroll
    for (int n = 0; n < 4; ++n)
#pragma unroll
      for (int j = 0; j < 4; ++j) {
        float hv = fmaxf(acc[m][n][j] * sc[n] + sh[n], 0.f);
        pj[j] += hv * wl[n];
        *(unsigned short*)(aw + (g * 4 + j) * 128 + (n * 16 + l15) * 2) = f2bf(hv);
      }
    // head partial: reduce across the 16 lanes (l15) of this g-group
#pragma unroll
    for (int j = 0; j < 4; ++j) {
      pj[j] += __shfl_xor(pj[j], 1);
      pj[j] += __shfl_xor(pj[j], 2);
      pj[j] += __shfl_xor(pj[j], 4);
      pj[j] += __shfl_xor(pj[j], 8);
    }
    if (l15 == 0) {
#pragma unroll
      for (int j = 0; j < 4; ++j)
        s_head[wr * 64 + m * 16 + g * 4 + j][wc] = pj[j];
    }
    // coalesced bf16 h store (wave-private LDS bounce; DS in-order, no barrier)
    int grb = row0 + m * 16;
#pragma unroll
    for (int it = 0; it < 2; ++it) {
      int bo = lane * 16 + it * 1024;
      int r16 = bo >> 7, inrow = bo & 127;
      if (grb + r16 < N)
        *(i32x4*)((char*)hout + (size_t)(grb + r16) * 256 + wc * 128 + inrow) =
            *(i32x4*)(aw + bo);
    }
  }
  __syncthreads();
  // finish head: one thread per block-row
  if (tid < 128) {
    int grh = blockIdx.x * 128 + tid;
    if (grh < N) {
      float np = s_head[tid][0] + s_head[tid][1] + blin[lidx];
      if (FIRST) node_pred[grh] = np; else node_pred[grh] += np;
      atomicMax(&s_wsi[batch[grh]], fenc(np));
    }
  }
  __syncthreads();
  if (tid < NGRAPH && s_wsi[tid] != 0u) atomicMax(&wsi[tid], s_wsi[tid]);
}

// tmp[i] = h[i] + sum_{j in-edges} h[src_j]   (bf16 storage, f32 accumulate)
__global__ void __launch_bounds__(256)
agg_kernel(const unsigned short* __restrict__ h, const int* __restrict__ offsets,
           const int* __restrict__ esrc, unsigned short* __restrict__ tmp, int n) {
  int node = blockIdx.x * 4 + (threadIdx.x >> 6);
  if (node >= n) return;
  int lane = threadIdx.x & 63;  // 2 features per lane
  const unsigned* hw = (const unsigned*)h;
  size_t base = (size_t)node * (H / 2) + lane;
  unsigned u = hw[base];
  float a0 = __uint_as_float((u & 0xFFFFu) << 16);
  float a1 = __uint_as_float(u & 0xFFFF0000u);
  int s = offsets[node], e = offsets[node + 1];
  int j = s;
  for (; j + 4 <= e; j += 4) {
    int i0 = esrc[j], i1 = esrc[j + 1], i2 = esrc[j + 2], i3 = esrc[j + 3];
    unsigned v0 = hw[(size_t)i0 * (H / 2) + lane];
    unsigned v1 = hw[(size_t)i1 * (H / 2) + lane];
    unsigned v2 = hw[(size_t)i2 * (H / 2) + lane];
    unsigned v3 = hw[(size_t)i3 * (H / 2) + lane];
    a0 += __uint_as_float((v0 & 0xFFFFu) << 16) + __uint_as_float((v1 & 0xFFFFu) << 16) +
          __uint_as_float((v2 & 0xFFFFu) << 16) + __uint_as_float((v3 & 0xFFFFu) << 16);
    a1 += __uint_as_float(v0 & 0xFFFF0000u) + __uint_as_float(v1 & 0xFFFF0000u) +
          __uint_as_float(v2 & 0xFFFF0000u) + __uint_as_float(v3 & 0xFFFF0000u);
  }
  for (; j < e; ++j) {
    unsigned v2 = hw[(size_t)esrc[j] * (H / 2) + lane];
    a0 += __uint_as_float((v2 & 0xFFFFu) << 16);
    a1 += __uint_as_float(v2 & 0xFFFF0000u);
  }
  unsigned r = ((unsigned)f2bf(a1) << 16) | (unsigned)f2bf(a0);
  ((unsigned*)tmp)[base] = r;
}

__global__ void finalize_kernel(const unsigned* __restrict__ wsi, float* __restrict__ out) {
  int g = threadIdx.x;
  if (g < NGRAPH) out[g] = fdec(wsi[g]) + fdec(wsi[NGRAPH + g]) + fdec(wsi[2 * NGRAPH + g]);
}

extern "C" void kernel_launch(void* const* d_in, const int* in_sizes, int n_in,
                              void* d_out, int out_size, void* d_ws, size_t ws_size,
                              hipStream_t stream) {
  const float* x        = (const float*)d_in[0];
  const int*   ei       = (const int*)d_in[1];
  const int*   batch    = (const int*)d_in[2];
  const float* w_first  = (const float*)d_in[3];
  const float* b_first  = (const float*)d_in[4];
  const float* bn_first = (const float*)d_in[5];
  const float* w_conv   = (const float*)d_in[6];
  const float* b_conv   = (const float*)d_in[7];
  const float* bn_conv  = (const float*)d_in[8];
  const float* w_lin    = (const float*)d_in[9];
  const float* b_lin    = (const float*)d_in[10];
  float* out = (float*)d_out;

  const int N = in_sizes[0] / D_IN;
  const int E = in_sizes[1] / 2;
  const int* src = ei;
  const int* dst = ei + E;

  char* ws = (char*)d_ws;
  unsigned short* h   = (unsigned short*)ws;            // N*H bf16
  unsigned short* tmp = h + (size_t)N * H;              // N*H bf16
  unsigned short* wTf = tmp + (size_t)N * H;            // 128*256 bf16 (w_first^T)
  unsigned short* wTc = wTf + H * D_IN;                 // 2*128*128 bf16 (w_conv^T)
  int* offsets = (int*)(wTc + 2 * H * H);
  int* cursor  = offsets + (N + 1);
  int* esrc    = cursor + N;
  int* bsum    = esrc + E;                              // scan block sums (<=128)
  unsigned* wsi = (unsigned*)(bsum + 128);
  float* node_pred = out + NGRAPH;

  const int gemm_grid = (N + 127) / 128;
  const int nscan = N + 1;
  const int nb = (nscan + 1023) / 1024;                 // 98 for N=100000 (must be <=128)

  init_kernel<<<(N + 256) / 256, 256, 0, stream>>>(offsets, wsi, N + 1);
  count_kernel<<<1024, 256, 0, stream>>>(dst, offsets, E);
  scan_local<<<nb, 1024, 0, stream>>>(offsets, bsum, nscan);
  scan_bsum<<<1, 128, 0, stream>>>(bsum, nb);
  scan_add<<<nb, 1024, 0, stream>>>(offsets, bsum, cursor, nscan, N);
  fill_kernel<<<1024, 256, 0, stream>>>(src, dst, cursor, esrc, E);
  prep_weights<<<256, 256, 0, stream>>>(w_first, w_conv, wTf, wTc);

  gemm_kernel<D_IN, true, true><<<gemm_grid, 256, 0, stream>>>(
      x, wTf, b_first, bn_first, w_lin, b_lin, 0, batch, h, node_pred, wsi, N);
  for (int l = 0; l < 2; ++l) {
    agg_kernel<<<(N + 3) / 4, 256, 0, stream>>>(h, offsets, esrc, tmp, N);
    gemm_kernel<H, false, false><<<gemm_grid, 256, 0, stream>>>(
        tmp, wTc + (size_t)l * H * H, b_conv + (size_t)l * H, bn_conv + (size_t)l * 4 * H,
        w_lin + (size_t)(l + 1) * H, b_lin, l + 1, batch, h, node_pred,
        wsi + (size_t)(l + 1) * NGRAPH, N);
  }
  finalize_kernel<<<1, 64, 0, stream>>>(wsi, out);
}

// Round 9
// 264.887 us; speedup vs baseline: 14.1118x; 1.0531x over previous
//
#include <hip/hip_runtime.h>
#include <hip/hip_bf16.h>

#define H 128
#define D_IN 256
#define NGRAPH 8

typedef __attribute__((ext_vector_type(8))) short bf16x8;
typedef __attribute__((ext_vector_type(4))) float f32x4;
typedef __attribute__((ext_vector_type(4))) int i32x4;

// ---- order-preserving float<->unsigned encoding for atomicMax-based segment_max
__device__ __forceinline__ unsigned fenc(float f) {
  unsigned u = __float_as_uint(f);
  return (u & 0x80000000u) ? ~u : (u | 0x80000000u);
}
__device__ __forceinline__ float fdec(unsigned e) {
  unsigned v = (e & 0x80000000u) ? (e & 0x7FFFFFFFu) : ~e;
  return __uint_as_float(v);
}
__device__ __forceinline__ unsigned short f2bf(float f) {  // RNE f32->bf16
  unsigned u = __float_as_uint(f);
  unsigned r = u + 0x7FFFu + ((u >> 16) & 1u);
  return (unsigned short)(r >> 16);
}

__global__ void init_kernel(int* __restrict__ offsets, unsigned* __restrict__ wsi, int n1) {
  int i = blockIdx.x * blockDim.x + threadIdx.x;
  if (i < n1) offsets[i] = 0;
  if (i < 3 * NGRAPH) wsi[i] = 0u;  // 0 < fenc(any finite float)
}

__global__ void count_kernel(const int* __restrict__ dst, int* __restrict__ offsets, int E) {
  int i = blockIdx.x * blockDim.x + threadIdx.x;
  int stride = gridDim.x * blockDim.x;
  for (int e = i; e < E; e += stride) atomicAdd(&offsets[dst[e]], 1);
}

// ---- hierarchical scan
__global__ void __launch_bounds__(1024)
scan_local(int* __restrict__ data, int* __restrict__ bsum, int n) {
  __shared__ int s[1024];
  int tid = threadIdx.x;
  int i = blockIdx.x * 1024 + tid;
  int v = (i < n) ? data[i] : 0;
  s[tid] = v;
  __syncthreads();
  for (int off = 1; off < 1024; off <<= 1) {
    int t = (tid >= off) ? s[tid - off] : 0;
    __syncthreads();
    s[tid] += t;
    __syncthreads();
  }
  if (i < n) data[i] = s[tid] - v;  // exclusive
  if (tid == 1023) bsum[blockIdx.x] = s[1023];
}

__global__ void __launch_bounds__(128)
scan_bsum(int* __restrict__ bsum, int nb) {
  __shared__ int s[128];
  int tid = threadIdx.x;
  int v = (tid < nb) ? bsum[tid] : 0;
  s[tid] = v;
  __syncthreads();
  for (int off = 1; off < 128; off <<= 1) {
    int t = (tid >= off) ? s[tid - off] : 0;
    __syncthreads();
    s[tid] += t;
    __syncthreads();
  }
  if (tid < nb) bsum[tid] = s[tid] - v;  // exclusive
}

__global__ void __launch_bounds__(1024)
scan_add(int* __restrict__ data, const int* __restrict__ bsum, int* __restrict__ cursor,
         int n, int ncur) {
  int i = blockIdx.x * 1024 + threadIdx.x;
  if (i < n) {
    int v = data[i] + bsum[blockIdx.x];
    data[i] = v;
    if (i < ncur) cursor[i] = v;
  }
}

__global__ void fill_kernel(const int* __restrict__ src, const int* __restrict__ dst,
                            int* __restrict__ cursor, int* __restrict__ esrc, int E) {
  int i = blockIdx.x * blockDim.x + threadIdx.x;
  int stride = gridDim.x * blockDim.x;
  for (int e = i; e < E; e += stride) {
    int d = dst[e];
    int p = atomicAdd(&cursor[d], 1);
    esrc[p] = src[e];
  }
}

// transpose + convert weights to bf16: wT[n][k] = bf16(w[k][n])
__global__ void prep_weights(const float* __restrict__ wf, const float* __restrict__ wcv,
                             unsigned short* __restrict__ wTf, unsigned short* __restrict__ wTc) {
  int i = blockIdx.x * 256 + threadIdx.x;
  if (i < H * D_IN) {
    int n = i >> 8, k = i & 255;
    wTf[i] = f2bf(wf[k * H + n]);
  } else if (i < H * D_IN + 2 * H * H) {
    int j = i - H * D_IN;
    int l = j >> 14, r = j & 16383;
    int n = r >> 7, k = r & 127;
    wTc[j] = f2bf(wcv[l * H * H + k * H + n]);
  }
}

// ---- pipeline stages (per k-step fragments held in registers)
struct af32_stage { float4 u0[4], u1[4]; };  // f32 A rows, pre-conversion
struct abf_stage  { i32x4 q[4]; };           // bf16 A fragments
struct b_stage    { i32x4 q[4]; };           // bf16 B fragments

__device__ __forceinline__ void issueA_f32(af32_stage& st, const char* const aptr[4], int s) {
#pragma unroll
  for (int m = 0; m < 4; ++m) {
    st.u0[m] = *(const float4*)(aptr[m] + s * 128);
    st.u1[m] = *(const float4*)(aptr[m] + s * 128 + 16);
  }
}
__device__ __forceinline__ void issueA_bf(abf_stage& st, const char* const aptr[4], int s) {
#pragma unroll
  for (int m = 0; m < 4; ++m) st.q[m] = *(const i32x4*)(aptr[m] + s * 64);
}
__device__ __forceinline__ void issueB(b_stage& st, const unsigned short* const bptr[4], int s) {
#pragma unroll
  for (int n = 0; n < 4; ++n) st.q[n] = *(const i32x4*)(bptr[n] + s * 32);
}
__device__ __forceinline__ void consume_f32(const af32_stage& st, const b_stage& bs,
                                            f32x4 (&acc)[4][4]) {
  bf16x8 af[4];
#pragma unroll
  for (int m = 0; m < 4; ++m) {
    union { unsigned short hh[8]; bf16x8 v; } pk;
    pk.hh[0] = f2bf(st.u0[m].x); pk.hh[1] = f2bf(st.u0[m].y);
    pk.hh[2] = f2bf(st.u0[m].z); pk.hh[3] = f2bf(st.u0[m].w);
    pk.hh[4] = f2bf(st.u1[m].x); pk.hh[5] = f2bf(st.u1[m].y);
    pk.hh[6] = f2bf(st.u1[m].z); pk.hh[7] = f2bf(st.u1[m].w);
    af[m] = pk.v;
  }
#pragma unroll
  for (int m = 0; m < 4; ++m)
#pragma unroll
    for (int n = 0; n < 4; ++n)
      acc[m][n] = __builtin_amdgcn_mfma_f32_16x16x32_bf16(af[m], *(const bf16x8*)&bs.q[n],
                                                          acc[m][n], 0, 0, 0);
}
__device__ __forceinline__ void consume_bf(const abf_stage& st, const b_stage& bs,
                                           f32x4 (&acc)[4][4]) {
#pragma unroll
  for (int m = 0; m < 4; ++m)
#pragma unroll
    for (int n = 0; n < 4; ++n)
      acc[m][n] = __builtin_amdgcn_mfma_f32_16x16x32_bf16(*(const bf16x8*)&st.q[m],
                                                          *(const bf16x8*)&bs.q[n],
                                                          acc[m][n], 0, 0, 0);
}

// Fused GEMM [N x K] @ [K x 128] + bias + BN(eval) + ReLU -> h (bf16),
// plus linear head -> node_pred and per-graph segment-max -> wsi.
// 4 waves in 2x2; wave tile 64x64; register-software-pipelined A/B loads,
// PINNED with sched_barrier(0) so the scheduler cannot sink the prefetches
// (round-6 lesson: without the pin, VGPR dropped to 72 and the pipeline
// was serialized away).
template <int K, bool AF32, bool FIRST>
__global__ void __launch_bounds__(256, 2)
gemm_kernel(const void* __restrict__ Ain, const unsigned short* __restrict__ wT,
            const float* __restrict__ bias, const float* __restrict__ bn,
            const float* __restrict__ wlin, const float* __restrict__ blin, int lidx,
            const int* __restrict__ batch, unsigned short* __restrict__ hout,
            float* __restrict__ node_pred, unsigned* __restrict__ wsi, int N) {
  __shared__ char s_tile[4][2048];     // per-wave h-store staging (16 rows x 64 cols bf16)
  __shared__ float s_head[128][2];     // per-row linear-head partials (wc halves)
  __shared__ unsigned s_wsi[NGRAPH];
  const int tid = threadIdx.x;
  const int wid = tid >> 6, lane = tid & 63;
  const int wr = wid >> 1, wc = wid & 1;
  const int g = lane >> 4, l15 = lane & 15;
  if (tid < NGRAPH) s_wsi[tid] = 0u;
  __syncthreads();

  const int row0 = blockIdx.x * 128 + wr * 64;
  f32x4 acc[4][4] = {};

  // per-m row base pointers (clamped rows: always-valid loads, result masked on store)
  const char* aptr[4];
#pragma unroll
  for (int m = 0; m < 4; ++m) {
    int r = row0 + m * 16 + l15;
    r = (r < N) ? r : (N - 1);
    aptr[m] = (const char*)Ain + (size_t)r * K * (AF32 ? 4 : 2) + g * (AF32 ? 32 : 16);
  }
  const unsigned short* bptr[4];
#pragma unroll
  for (int n = 0; n < 4; ++n) {
    int c = wc * 64 + n * 16 + l15;
    bptr[n] = wT + (size_t)c * K + g * 8;
  }

  if constexpr (!AF32) {
    // K == 128: issue ALL 32 loads (4 A stages + 4 B stages), pin, then consume.
    abf_stage a0, a1, a2, a3;
    b_stage b0, b1, b2, b3;
    issueA_bf(a0, aptr, 0); issueA_bf(a1, aptr, 1);
    issueA_bf(a2, aptr, 2); issueA_bf(a3, aptr, 3);
    issueB(b0, bptr, 0); issueB(b1, bptr, 1);
    issueB(b2, bptr, 2); issueB(b3, bptr, 3);
    __builtin_amdgcn_sched_barrier(0);  // do NOT sink the loads below this point
    consume_bf(a0, b0, acc); consume_bf(a1, b1, acc);
    consume_bf(a2, b2, acc); consume_bf(a3, b3, acc);
  } else {
    // K == 256: 2-deep rotating pipeline over 8 k-steps; pin after every issue group.
    af32_stage a0, a1;
    b_stage b0, b1;
    issueA_f32(a0, aptr, 0); issueB(b0, bptr, 0);
    issueA_f32(a1, aptr, 1); issueB(b1, bptr, 1);
    __builtin_amdgcn_sched_barrier(0);
    consume_f32(a0, b0, acc); issueA_f32(a0, aptr, 2); issueB(b0, bptr, 2);
    __builtin_amdgcn_sched_barrier(0);
    consume_f32(a1, b1, acc); issueA_f32(a1, aptr, 3); issueB(b1, bptr, 3);
    __builtin_amdgcn_sched_barrier(0);
    consume_f32(a0, b0, acc); issueA_f32(a0, aptr, 4); issueB(b0, bptr, 4);
    __builtin_amdgcn_sched_barrier(0);
    consume_f32(a1, b1, acc); issueA_f32(a1, aptr, 5); issueB(b1, bptr, 5);
    __builtin_amdgcn_sched_barrier(0);
    consume_f32(a0, b0, acc); issueA_f32(a0, aptr, 6); issueB(b0, bptr, 6);
    __builtin_amdgcn_sched_barrier(0);
    consume_f32(a1, b1, acc); issueA_f32(a1, aptr, 7); issueB(b1, bptr, 7);
    __builtin_amdgcn_sched_barrier(0);
    consume_f32(a0, b0, acc);
    consume_f32(a1, b1, acc);
  }

  // ---- epilogue: bias+BN+ReLU folded to hv = acc*sc + sh
  float sc[4], sh[4], wl[4];
#pragma unroll
  for (int n = 0; n < 4; ++n) {
    int c = wc * 64 + n * 16 + l15;
    float gam = bn[c], bet = bn[H + c], mu = bn[2 * H + c], va = bn[3 * H + c];
    float rs = rsqrtf(va + 1e-5f);
    sc[n] = gam * rs;
    sh[n] = (bias[c] - mu) * gam * rs + bet;
    wl[n] = wlin[c];
  }

  char* aw = s_tile[wid];
#pragma unroll
  for (int m = 0; m < 4; ++m) {
    float pj[4] = {0.f, 0.f, 0.f, 0.f};
#pragma unroll
    for (int n = 0; n < 4; ++n)
#pragma unroll
      for (int j = 0; j < 4; ++j) {
        float hv = fmaxf(acc[m][n][j] * sc[n] + sh[n], 0.f);
        pj[j] += hv * wl[n];
        *(unsigned short*)(aw + (g * 4 + j) * 128 + (n * 16 + l15) * 2) = f2bf(hv);
      }
    // head partial: reduce across the 16 lanes (l15) of this g-group
#pragma unroll
    for (int j = 0; j < 4; ++j) {
      pj[j] += __shfl_xor(pj[j], 1);
      pj[j] += __shfl_xor(pj[j], 2);
      pj[j] += __shfl_xor(pj[j], 4);
      pj[j] += __shfl_xor(pj[j], 8);
    }
    if (l15 == 0) {
#pragma unroll
      for (int j = 0; j < 4; ++j)
        s_head[wr * 64 + m * 16 + g * 4 + j][wc] = pj[j];
    }
    // coalesced bf16 h store (wave-private LDS bounce; DS in-order, no barrier)
    int grb = row0 + m * 16;
#pragma unroll
    for (int it = 0; it < 2; ++it) {
      int bo = lane * 16 + it * 1024;
      int r16 = bo >> 7, inrow = bo & 127;
      if (grb + r16 < N)
        *(i32x4*)((char*)hout + (size_t)(grb + r16) * 256 + wc * 128 + inrow) =
            *(i32x4*)(aw + bo);
    }
  }
  __syncthreads();
  // finish head: one thread per block-row
  if (tid < 128) {
    int grh = blockIdx.x * 128 + tid;
    if (grh < N) {
      float np = s_head[tid][0] + s_head[tid][1] + blin[lidx];
      if (FIRST) node_pred[grh] = np; else node_pred[grh] += np;
      atomicMax(&s_wsi[batch[grh]], fenc(np));
    }
  }
  __syncthreads();
  if (tid < NGRAPH && s_wsi[tid] != 0u) atomicMax(&wsi[tid], s_wsi[tid]);
}

// tmp[i] = h[i] + sum_{j in-edges} h[src_j]   (bf16 storage, f32 accumulate)
__global__ void __launch_bounds__(256)
agg_kernel(const unsigned short* __restrict__ h, const int* __restrict__ offsets,
           const int* __restrict__ esrc, unsigned short* __restrict__ tmp, int n) {
  int node = blockIdx.x * 4 + (threadIdx.x >> 6);
  if (node >= n) return;
  int lane = threadIdx.x & 63;  // 2 features per lane
  const unsigned* hw = (const unsigned*)h;
  size_t base = (size_t)node * (H / 2) + lane;
  unsigned u = hw[base];
  float a0 = __uint_as_float((u & 0xFFFFu) << 16);
  float a1 = __uint_as_float(u & 0xFFFF0000u);
  int s = offsets[node], e = offsets[node + 1];
  int j = s;
  for (; j + 4 <= e; j += 4) {
    int i0 = esrc[j], i1 = esrc[j + 1], i2 = esrc[j + 2], i3 = esrc[j + 3];
    unsigned v0 = hw[(size_t)i0 * (H / 2) + lane];
    unsigned v1 = hw[(size_t)i1 * (H / 2) + lane];
    unsigned v2 = hw[(size_t)i2 * (H / 2) + lane];
    unsigned v3 = hw[(size_t)i3 * (H / 2) + lane];
    a0 += __uint_as_float((v0 & 0xFFFFu) << 16) + __uint_as_float((v1 & 0xFFFFu) << 16) +
          __uint_as_float((v2 & 0xFFFFu) << 16) + __uint_as_float((v3 & 0xFFFFu) << 16);
    a1 += __uint_as_float(v0 & 0xFFFF0000u) + __uint_as_float(v1 & 0xFFFF0000u) +
          __uint_as_float(v2 & 0xFFFF0000u) + __uint_as_float(v3 & 0xFFFF0000u);
  }
  for (; j < e; ++j) {
    unsigned v2 = hw[(size_t)esrc[j] * (H / 2) + lane];
    a0 += __uint_as_float((v2 & 0xFFFFu) << 16);
    a1 += __uint_as_float(v2 & 0xFFFF0000u);
  }
  unsigned r = ((unsigned)f2bf(a1) << 16) | (unsigned)f2bf(a0);
  ((unsigned*)tmp)[base] = r;
}

__global__ void finalize_kernel(const unsigned* __restrict__ wsi, float* __restrict__ out) {
  int g = threadIdx.x;
  if (g < NGRAPH) out[g] = fdec(wsi[g]) + fdec(wsi[NGRAPH + g]) + fdec(wsi[2 * NGRAPH + g]);
}

extern "C" void kernel_launch(void* const* d_in, const int* in_sizes, int n_in,
                              void* d_out, int out_size, void* d_ws, size_t ws_size,
                              hipStream_t stream) {
  const float* x        = (const float*)d_in[0];
  const int*   ei       = (const int*)d_in[1];
  const int*   batch    = (const int*)d_in[2];
  const float* w_first  = (const float*)d_in[3];
  const float* b_first  = (const float*)d_in[4];
  const float* bn_first = (const float*)d_in[5];
  const float* w_conv   = (const float*)d_in[6];
  const float* b_conv   = (const float*)d_in[7];
  const float* bn_conv  = (const float*)d_in[8];
  const float* w_lin    = (const float*)d_in[9];
  const float* b_lin    = (const float*)d_in[10];
  float* out = (float*)d_out;

  const int N = in_sizes[0] / D_IN;
  const int E = in_sizes[1] / 2;
  const int* src = ei;
  const int* dst = ei + E;

  char* ws = (char*)d_ws;
  unsigned short* h   = (unsigned short*)ws;            // N*H bf16
  unsigned short* tmp = h + (size_t)N * H;              // N*H bf16
  unsigned short* wTf = tmp + (size_t)N * H;            // 128*256 bf16 (w_first^T)
  unsigned short* wTc = wTf + H * D_IN;                 // 2*128*128 bf16 (w_conv^T)
  int* offsets = (int*)(wTc + 2 * H * H);
  int* cursor  = offsets + (N + 1);
  int* esrc    = cursor + N;
  int* bsum    = esrc + E;                              // scan block sums (<=128)
  unsigned* wsi = (unsigned*)(bsum + 128);
  float* node_pred = out + NGRAPH;

  const int gemm_grid = (N + 127) / 128;
  const int nscan = N + 1;
  const int nb = (nscan + 1023) / 1024;                 // 98 for N=100000 (must be <=128)

  init_kernel<<<(N + 256) / 256, 256, 0, stream>>>(offsets, wsi, N + 1);
  count_kernel<<<1024, 256, 0, stream>>>(dst, offsets, E);
  scan_local<<<nb, 1024, 0, stream>>>(offsets, bsum, nscan);
  scan_bsum<<<1, 128, 0, stream>>>(bsum, nb);
  scan_add<<<nb, 1024, 0, stream>>>(offsets, bsum, cursor, nscan, N);
  fill_kernel<<<1024, 256, 0, stream>>>(src, dst, cursor, esrc, E);
  prep_weights<<<256, 256, 0, stream>>>(w_first, w_conv, wTf, wTc);

  gemm_kernel<D_IN, true, true><<<gemm_grid, 256, 0, stream>>>(
      x, wTf, b_first, bn_first, w_lin, b_lin, 0, batch, h, node_pred, wsi, N);
  for (int l = 0; l < 2; ++l) {
    agg_kernel<<<(N + 3) / 4, 256, 0, stream>>>(h, offsets, esrc, tmp, N);
    gemm_kernel<H, false, false><<<gemm_grid, 256, 0, stream>>>(
        tmp, wTc + (size_t)l * H * H, b_conv + (size_t)l * H, bn_conv + (size_t)l * 4 * H,
        w_lin + (size_t)(l + 1) * H, b_lin, l + 1, batch, h, node_pred,
        wsi + (size_t)(l + 1) * NGRAPH, N);
  }
  finalize_kernel<<<1, 64, 0, stream>>>(wsi, out);
}